// Round 22
// baseline (72.325 us; speedup 1.0000x reference)
//
#include <hip/hip_runtime.h>

#define NROWS 131072          // 64*2048
#define D 64
#define K 512
#define TPB 128               // 2 waves/block
#define RPB 64                // 2 waves x 32 rows each (mt=2)
#define NBLK (NROWS/RPB)      // 2048 blocks -> 8 blocks/CU schedulable

#define LOSS_OFF (NROWS*D)    // 8388608
#define PERP_OFF (LOSS_OFF+1)
#define IDX_OFF  (LOSS_OFF+2)

typedef _Float16 h16x8 __attribute__((ext_vector_type(8)));  // 8 fp16 (4 VGPR)
typedef float    f32x4 __attribute__((ext_vector_type(4)));  // MFMA acc

// ws: [0] f32 wsum | [256B] int hist[512] | [4096B] f32 e2[512] | [8192B] bfrag 131072B

// fp16 two-way split with scaled residual: v = h + 2^-12 * m' (see R13).
__device__ __forceinline__ void split8_f16(float4 a, float4 b,
                                           h16x8* h8, h16x8* m8)
{
    float xf[8] = {a.x,a.y,a.z,a.w,b.x,b.y,b.z,b.w};
    _Float16 hh[8], mm[8];
    #pragma unroll
    for (int j = 0; j < 8; ++j) {
        float v = xf[j];
        _Float16 h = (_Float16)v;                 // RTN
        float hf = (float)h;
        if (fabsf(hf) < 6.1035156e-5f) { h = (_Float16)0.f; hf = 0.f; }
        hh[j] = h;
        mm[j] = (_Float16)((v - hf) * 4096.f);    // m' = 2^12 * residual
    }
    *h8 = (h16x8){hh[0],hh[1],hh[2],hh[3],hh[4],hh[5],hh[6],hh[7]};
    *m8 = (h16x8){mm[0],mm[1],mm[2],mm[3],mm[4],mm[5],mm[6],mm[7]};
}

// prep: pack fp16 splits of (-2*codebook) into B-fragment order + fp32 e2.
// Block 0 additionally zeroes wsum + whist.
__global__ __launch_bounds__(64) void vq_prep(
    const float* __restrict__ emb, float* __restrict__ e2, h16x8* __restrict__ bfrag,
    float* __restrict__ wsum, int* __restrict__ whist)
{
    const int ct = blockIdx.x, l = threadIdx.x;      // 32 blocks x 64
    if (ct == 0) {
        if (l == 0) wsum[0] = 0.f;
        #pragma unroll
        for (int i = l; i < K; i += 64) whist[i] = 0;
    }
    const int q = l >> 4, r16 = l & 15;
    const int code = ct*16 + r16;
    const float4* e4 = reinterpret_cast<const float4*>(emb + (size_t)code * D);
    #pragma unroll
    for (int s = 0; s < 2; ++s) {
        float4 f0 = e4[q*2 + s*8];
        float4 f1 = e4[q*2 + s*8 + 1];
        float4 g0 = {-2.f*f0.x, -2.f*f0.y, -2.f*f0.z, -2.f*f0.w};
        float4 g1 = {-2.f*f1.x, -2.f*f1.y, -2.f*f1.z, -2.f*f1.w};
        h16x8 g, n;
        split8_f16(g0, g1, &g, &n);
        bfrag[(ct*4 + 0 + s)*64 + l] = g;
        bfrag[(ct*4 + 2 + s)*64 + l] = n;
    }
    if (l < 16) {
        const float* e = emb + (size_t)(ct*16 + l) * D;
        float s0=0.f,s1=0.f,s2=0.f,s3=0.f;
        #pragma unroll
        for (int d = 0; d < D; d += 4) {
            s0 = fmaf(e[d+0], e[d+0], s0);
            s1 = fmaf(e[d+1], e[d+1], s1);
            s2 = fmaf(e[d+2], e[d+2], s2);
            s3 = fmaf(e[d+3], e[d+3], s3);
        }
        e2[ct*16 + l] = (s0+s1)+(s2+s3);
    }
}

#define MFMA_(AV, BV, CI) __builtin_amdgcn_mfma_f32_16x16x32_f16((AV), (BV), (CI), 0, 0, 0)

// load B-fragment set for tile CT from global (L2-hot, stays in flight)
#define LOADB(B0,B1,B2,B3,E2V, CT) do {                             \
    const h16x8* _bp = bbase + (size_t)(CT)*4*64;                   \
    B0 = _bp[0*64]; B1 = _bp[1*64];                                 \
    B2 = _bp[2*64]; B3 = _bp[3*64];                                 \
    E2V = e2g[((CT) << 4) + r16];                                   \
} while (0)

// 12 MFMAs: two row-frags (mt=0,1) share one B set.
// chainA = h.g (seeded e2); chainB = h.n' + m'.g (seeded 0).
#define UNIT_MFMA(SA0,SB0,SA1,SB1, B0,B1,B2,B3,E2V) do {              \
    f32x4 _ci = {(E2V),(E2V),(E2V),(E2V)};                            \
    SA0 = MFMA_(Ah[0][0], B0, _ci);   SA1 = MFMA_(Ah[1][0], B0, _ci);  \
    SB0 = MFMA_(Ah[0][0], B2, zero4); SB1 = MFMA_(Ah[1][0], B2, zero4);\
    SA0 = MFMA_(Ah[0][1], B1, SA0);   SA1 = MFMA_(Ah[1][1], B1, SA1);  \
    SB0 = MFMA_(Am[0][0], B0, SB0);   SB1 = MFMA_(Am[1][0], B0, SB1);  \
    SB0 = MFMA_(Ah[0][1], B3, SB0);   SB1 = MFMA_(Ah[1][1], B3, SB1);  \
    SB0 = MFMA_(Am[0][1], B1, SB0);   SB1 = MFMA_(Am[1][1], B1, SB1);  \
} while (0)

// running argmin on a FINISHED acc set (overlaps the other set's MFMAs)
#define UNIT_ARGMIN(SA0,SB0,SA1,SB1, CT) do {                         \
    const int _col = ((CT) << 4) + r16;                               \
    _Pragma("unroll")                                                 \
    for (int g = 0; g < 4; ++g) {                                     \
        float dst0 = fmaf(SB0[g], 2.44140625e-4f, SA0[g]);            \
        if (dst0 < bestd[0][g]) { bestd[0][g] = dst0; besti[0][g] = _col; } \
        float dst1 = fmaf(SB1[g], 2.44140625e-4f, SA1[g]);            \
        if (dst1 < bestd[1][g]) { bestd[1][g] = dst1; besti[1][g] = _col; } \
    }                                                                 \
} while (0)

__global__ __launch_bounds__(TPB, 1) void vq_main(
    const float* __restrict__ x, const float* __restrict__ emb,
    const float* __restrict__ e2g, const h16x8* __restrict__ bfrag,
    float* __restrict__ out, float* __restrict__ wsum, int* __restrict__ whist)
{
    __shared__ int   shist[K];
    __shared__ int   sidx[RPB];
    __shared__ float sred[2];

    const int t = threadIdx.x;
    for (int i = t; i < K; i += TPB) shist[i] = 0;

    const int l = t & 63, w = t >> 6;           // 2 waves
    const int q = l >> 4, r16 = l & 15;
    const float4* x4 = reinterpret_cast<const float4*>(x);
    const int wbase = blockIdx.x * RPB + w * 32;

    // A fragments from global: [mt][kstep] h/m', row = wbase + mt*16 + r16
    h16x8 Ah[2][2], Am[2][2];
    #pragma unroll
    for (int mt = 0; mt < 2; ++mt) {
        #pragma unroll
        for (int s = 0; s < 2; ++s) {
            int rl = wbase + mt*16 + r16;
            float4 f0 = x4[(size_t)rl*16 + q*2 + s*8];
            float4 f1 = x4[(size_t)rl*16 + q*2 + s*8 + 1];
            split8_f16(f0, f1, &Ah[mt][s], &Am[mt][s]);
        }
    }

    float bestd[2][4];
    int   besti[2][4];
    #pragma unroll
    for (int mt = 0; mt < 2; ++mt)
        #pragma unroll
        for (int g = 0; g < 4; ++g) { bestd[mt][g] = 3.4e38f; besti[mt][g] = 0; }

    const h16x8* bbase = bfrag + l;
    const f32x4 zero4 = {0.f,0.f,0.f,0.f};

    // B double-buffer (P even / Q odd) + acc double-buffer (E/O), R20 schedule
    h16x8 p0,p1,p2,p3; float pe2;
    h16x8 q0,q1,q2,q3; float qe2;
    f32x4 eSA0,eSB0,eSA1,eSB1;
    f32x4 oSA0,oSB0,oSA1,oSB1;

    LOADB(p0,p1,p2,p3,pe2, 0);
    LOADB(q0,q1,q2,q3,qe2, 1);
    UNIT_MFMA(eSA0,eSB0,eSA1,eSB1, p0,p1,p2,p3,pe2);   // tile 0
    LOADB(p0,p1,p2,p3,pe2, 2);

    #pragma clang loop unroll(disable)
    for (int ct = 1; ct < 31; ct += 2) {
        UNIT_MFMA(oSA0,oSB0,oSA1,oSB1, q0,q1,q2,q3,qe2);   // tile ct
        LOADB(q0,q1,q2,q3,qe2, (ct + 2) & 31);
        UNIT_ARGMIN(eSA0,eSB0,eSA1,eSB1, ct - 1);          // overlaps O MFMAs
        UNIT_MFMA(eSA0,eSB0,eSA1,eSB1, p0,p1,p2,p3,pe2);   // tile ct+1
        LOADB(p0,p1,p2,p3,pe2, (ct + 3) & 31);             // ct=29: wraps, dead
        UNIT_ARGMIN(oSA0,oSB0,oSA1,oSB1, ct);              // overlaps E MFMAs
    }
    UNIT_MFMA(oSA0,oSB0,oSA1,oSB1, q0,q1,q2,q3,qe2);       // tile 31
    UNIT_ARGMIN(eSA0,eSB0,eSA1,eSB1, 30);
    UNIT_ARGMIN(oSA0,oSB0,oSA1,oSB1, 31);

    // cross-lane argmin over the 16 cols held by lanes sharing q (bits 0-3)
    #pragma unroll
    for (int mask = 1; mask <= 8; mask <<= 1) {
        #pragma unroll
        for (int mt = 0; mt < 2; ++mt)
            #pragma unroll
            for (int g = 0; g < 4; ++g) {
                float od = __shfl_xor(bestd[mt][g], mask, 64);
                int   oi = __shfl_xor(besti[mt][g], mask, 64);
                if (od < bestd[mt][g] ||
                    (od == bestd[mt][g] && oi < besti[mt][g])) {
                    bestd[mt][g] = od; besti[mt][g] = oi;
                }
            }
    }
    if (r16 == 0) {
        #pragma unroll
        for (int mt = 0; mt < 2; ++mt)
            #pragma unroll
            for (int g = 0; g < 4; ++g)
                sidx[w*32 + mt*16 + q*4 + g] = besti[mt][g];
    }
    __syncthreads();

    // fused epilogue: 2 threads/row, 32 elems each (x from global/L3, code L2)
    const int row = t >> 1, half = t & 1;
    const int grow = blockIdx.x * RPB + row;
    const int bi = sidx[row];
    float dsum = 0.f;
    {
        const float4* eq = reinterpret_cast<const float4*>(emb + (size_t)bi * D) + half*8;
        const float4* xg = x4 + (size_t)grow*16 + half*8;
        float4* o = reinterpret_cast<float4*>(out + (size_t)grow * D) + half*8;
        #pragma unroll
        for (int i = 0; i < 8; ++i) {
            float4 xv = xg[i];
            float4 qv = eq[i];
            float4 v;
            float d0,d1,d2,d3;
            d0 = qv.x - xv.x; v.x = xv.x + d0; dsum = fmaf(d0,d0,dsum);
            d1 = qv.y - xv.y; v.y = xv.y + d1; dsum = fmaf(d1,d1,dsum);
            d2 = qv.z - xv.z; v.z = xv.z + d2; dsum = fmaf(d2,d2,dsum);
            d3 = qv.w - xv.w; v.w = xv.w + d3; dsum = fmaf(d3,d3,dsum);
            o[i] = v;
        }
    }
    if (half == 0) {
        out[IDX_OFF + grow] = (float)bi;
        atomicAdd(&shist[bi], 1);
    }

    // wave reduce dsum, then block reduce via LDS -> 1 global atomic per block
    #pragma unroll
    for (int off = 32; off > 0; off >>= 1)
        dsum += __shfl_xor(dsum, off, 64);
    if (l == 0) sred[w] = dsum;
    __syncthreads();
    if (t == 0)
        atomicAdd(wsum, sred[0] + sred[1]);

    for (int i = t; i < K; i += TPB)
        if (shist[i]) atomicAdd(&whist[i], shist[i]);
}

__global__ __launch_bounds__(K) void vq_finalize(
    const float* __restrict__ wsum, const int* __restrict__ whist,
    float* __restrict__ out)
{
    __shared__ float red[K];
    int t = threadIdx.x;
    float c = (float)whist[t];
    float p = c / (float)NROWS;
    red[t] = p * logf(p + 1e-10f);
    __syncthreads();
    for (int s = K/2; s > 0; s >>= 1) {
        if (t < s) red[t] += red[t+s];
        __syncthreads();
    }
    if (t == 0) {
        out[PERP_OFF] = expf(-red[0]);
        out[LOSS_OFF] = 0.25f * (wsum[0] / (float)(NROWS*D));
    }
}

extern "C" void kernel_launch(void* const* d_in, const int* in_sizes, int n_in,
                              void* d_out, int out_size, void* d_ws, size_t ws_size,
                              hipStream_t stream)
{
    const float* x   = (const float*)d_in[0];
    const float* emb = (const float*)d_in[1];
    float* out   = (float*)d_out;
    float* wsum  = (float*)d_ws;                           // @0
    int*   whist = (int*)((char*)d_ws + 256);              // @256B
    float* e2    = (float*)((char*)d_ws + 4096);           // @4096B
    h16x8* bfrag = (h16x8*)((char*)d_ws + 8192);           // @8192B, 131072B

    vq_prep<<<32, 64, 0, stream>>>(emb, e2, bfrag, wsum, whist);  // also zeroes ws
    vq_main<<<NBLK, TPB, 0, stream>>>(x, emb, e2, bfrag, out, wsum, whist);
    vq_finalize<<<1, K, 0, stream>>>(wsum, whist, out);
}

// Round 23
// 67.491 us; speedup vs baseline: 1.0716x; 1.0716x over previous
//
#include <hip/hip_runtime.h>

#define NROWS 131072          // 64*2048
#define D 64
#define K 512
#define TPB 256               // 4 waves/block
#define RPB 64                // 4 waves x 16 rows each
#define NBLK (NROWS/RPB)      // 2048 blocks -> 8 blocks/CU by grid

#define LOSS_OFF (NROWS*D)    // 8388608
#define PERP_OFF (LOSS_OFF+1)
#define IDX_OFF  (LOSS_OFF+2)

typedef _Float16 h16x8 __attribute__((ext_vector_type(8)));  // 8 fp16 (4 VGPR)
typedef float    f32x4 __attribute__((ext_vector_type(4)));  // MFMA acc

// ws: [0] f32 wsum | [256B] int hist[512] | [4096B] f32 e2[512] | [8192B] bfrag 131072B

// fp16 two-way split with scaled residual: v = h + 2^-12 * m' (see R13).
__device__ __forceinline__ void split8_f16(float4 a, float4 b,
                                           h16x8* h8, h16x8* m8)
{
    float xf[8] = {a.x,a.y,a.z,a.w,b.x,b.y,b.z,b.w};
    _Float16 hh[8], mm[8];
    #pragma unroll
    for (int j = 0; j < 8; ++j) {
        float v = xf[j];
        _Float16 h = (_Float16)v;                 // RTN
        float hf = (float)h;
        if (fabsf(hf) < 6.1035156e-5f) { h = (_Float16)0.f; hf = 0.f; }
        hh[j] = h;
        mm[j] = (_Float16)((v - hf) * 4096.f);    // m' = 2^12 * residual
    }
    *h8 = (h16x8){hh[0],hh[1],hh[2],hh[3],hh[4],hh[5],hh[6],hh[7]};
    *m8 = (h16x8){mm[0],mm[1],mm[2],mm[3],mm[4],mm[5],mm[6],mm[7]};
}

// prep: pack fp16 splits of (-2*codebook) into B-fragment order + fp32 e2.
// Block 0 additionally zeroes wsum + whist (replaces a host memset launch).
__global__ __launch_bounds__(64) void vq_prep(
    const float* __restrict__ emb, float* __restrict__ e2, h16x8* __restrict__ bfrag,
    float* __restrict__ wsum, int* __restrict__ whist)
{
    const int ct = blockIdx.x, l = threadIdx.x;      // 32 blocks x 64
    if (ct == 0) {
        if (l == 0) wsum[0] = 0.f;
        #pragma unroll
        for (int i = l; i < K; i += 64) whist[i] = 0;
    }
    const int q = l >> 4, r16 = l & 15;
    const int code = ct*16 + r16;
    const float4* e4 = reinterpret_cast<const float4*>(emb + (size_t)code * D);
    #pragma unroll
    for (int s = 0; s < 2; ++s) {
        float4 f0 = e4[q*2 + s*8];
        float4 f1 = e4[q*2 + s*8 + 1];
        float4 g0 = {-2.f*f0.x, -2.f*f0.y, -2.f*f0.z, -2.f*f0.w};
        float4 g1 = {-2.f*f1.x, -2.f*f1.y, -2.f*f1.z, -2.f*f1.w};
        h16x8 g, n;
        split8_f16(g0, g1, &g, &n);
        bfrag[(ct*4 + 0 + s)*64 + l] = g;
        bfrag[(ct*4 + 2 + s)*64 + l] = n;
    }
    if (l < 16) {
        const float* e = emb + (size_t)(ct*16 + l) * D;
        float s0=0.f,s1=0.f,s2=0.f,s3=0.f;
        #pragma unroll
        for (int d = 0; d < D; d += 4) {
            s0 = fmaf(e[d+0], e[d+0], s0);
            s1 = fmaf(e[d+1], e[d+1], s1);
            s2 = fmaf(e[d+2], e[d+2], s2);
            s3 = fmaf(e[d+3], e[d+3], s3);
        }
        e2[ct*16 + l] = (s0+s1)+(s2+s3);
    }
}

#define MFMA_(AV, BV, CI) __builtin_amdgcn_mfma_f32_16x16x32_f16((AV), (BV), (CI), 0, 0, 0)

// load B-fragment set for tile CT from global (L2-hot, stays in flight)
#define LOADB(B0,B1,B2,B3,E2V, CT) do {                             \
    const h16x8* _bp = bbase + (size_t)(CT)*4*64;                   \
    B0 = _bp[0*64]; B1 = _bp[1*64];                                 \
    B2 = _bp[2*64]; B3 = _bp[3*64];                                 \
    E2V = e2g[((CT) << 4) + r16];                                   \
} while (0)

// 6 MFMAs: chainA = h.g (seeded e2); chainB = h.n' + m'.g (seeded 0).
#define UNIT_MFMA(SA,SB, B0,B1,B2,B3,E2V) do {                      \
    f32x4 _ci = {(E2V),(E2V),(E2V),(E2V)};                          \
    SA = MFMA_(Ah[0], B0, _ci);                                     \
    SB = MFMA_(Ah[0], B2, zero4);                                   \
    SA = MFMA_(Ah[1], B1, SA);                                      \
    SB = MFMA_(Am[0], B0, SB);                                      \
    SB = MFMA_(Ah[1], B3, SB);                                      \
    SB = MFMA_(Am[1], B1, SB);                                      \
} while (0)

// running argmin on a FINISHED acc set (runs while the other set's MFMAs fly)
#define UNIT_ARGMIN(SA,SB, CT) do {                                 \
    const int _col = ((CT) << 4) + r16;                             \
    _Pragma("unroll")                                               \
    for (int g = 0; g < 4; ++g) {                                   \
        float dst = fmaf(SB[g], 2.44140625e-4f, SA[g]);             \
        if (dst < bestd[g]) { bestd[g] = dst; besti[g] = _col; }    \
    }                                                               \
} while (0)

__global__ __launch_bounds__(TPB, 1) void vq_main(
    const float* __restrict__ x, const float* __restrict__ emb,
    const float* __restrict__ e2g, const h16x8* __restrict__ bfrag,
    float* __restrict__ out, float* __restrict__ wsum, int* __restrict__ whist)
{
    __shared__ int   shist[K];
    __shared__ int   sidx[RPB];
    __shared__ float sred[4];

    const int t = threadIdx.x;
    for (int i = t; i < K; i += TPB) shist[i] = 0;

    const int l = t & 63, w = t >> 6;           // 4 waves
    const int q = l >> 4, r16 = l & 15;
    const float4* x4 = reinterpret_cast<const float4*>(x);
    const int rowbase = blockIdx.x * RPB + w * 16;

    // A fragments from global: [kstep] h/m', row = rowbase + r16
    h16x8 Ah[2], Am[2];
    #pragma unroll
    for (int s = 0; s < 2; ++s) {
        int rl = rowbase + r16;
        float4 f0 = x4[(size_t)rl*16 + q*2 + s*8];
        float4 f1 = x4[(size_t)rl*16 + q*2 + s*8 + 1];
        split8_f16(f0, f1, &Ah[s], &Am[s]);
    }

    float bestd[4];
    int   besti[4];
    #pragma unroll
    for (int g = 0; g < 4; ++g) { bestd[g] = 3.4e38f; besti[g] = 0; }

    const h16x8* bbase = bfrag + l;
    const f32x4 zero4 = {0.f,0.f,0.f,0.f};

    // B quad-buffer (P,Q,R,S: distance-4 prefetch) + acc double-buffer
    // (E = even tiles, O = odd tiles).
    h16x8 p0,p1,p2,p3; float pe2;
    h16x8 q0,q1,q2,q3; float qe2;
    h16x8 r0,r1,r2,r3; float re2;
    h16x8 s0,s1,s2,s3; float se2v;
    f32x4 eSA,eSB, oSA,oSB;

    LOADB(p0,p1,p2,p3,pe2, 0);
    LOADB(q0,q1,q2,q3,qe2, 1);
    LOADB(r0,r1,r2,r3,re2, 2);
    LOADB(s0,s1,s2,s3,se2v, 3);
    UNIT_MFMA(eSA,eSB, p0,p1,p2,p3,pe2);         // tile 0 (E)
    LOADB(p0,p1,p2,p3,pe2, 4);

    #pragma clang loop unroll(disable)
    for (int ct = 1; ct < 29; ct += 4) {
        UNIT_MFMA(oSA,oSB, q0,q1,q2,q3,qe2);     // tile ct   (O)
        LOADB(q0,q1,q2,q3,qe2, (ct + 4) & 31);
        UNIT_ARGMIN(eSA,eSB, ct - 1);
        UNIT_MFMA(eSA,eSB, r0,r1,r2,r3,re2);     // tile ct+1 (E)
        LOADB(r0,r1,r2,r3,re2, (ct + 5) & 31);
        UNIT_ARGMIN(oSA,oSB, ct);
        UNIT_MFMA(oSA,oSB, s0,s1,s2,s3,se2v);    // tile ct+2 (O)
        LOADB(s0,s1,s2,s3,se2v, (ct + 6) & 31);
        UNIT_ARGMIN(eSA,eSB, ct + 1);
        UNIT_MFMA(eSA,eSB, p0,p1,p2,p3,pe2);     // tile ct+3 (E)
        LOADB(p0,p1,p2,p3,pe2, (ct + 7) & 31);   // ct=25: tile 32 -> wraps 0, dead
        UNIT_ARGMIN(oSA,oSB, ct + 2);
    }
    // tiles 29(Q,O), 30(R,E), 31(S,O); argmin stays ascending
    UNIT_MFMA(oSA,oSB, q0,q1,q2,q3,qe2);         // tile 29
    UNIT_ARGMIN(eSA,eSB, 28);
    UNIT_MFMA(eSA,eSB, r0,r1,r2,r3,re2);         // tile 30
    UNIT_ARGMIN(oSA,oSB, 29);
    UNIT_MFMA(oSA,oSB, s0,s1,s2,s3,se2v);        // tile 31
    UNIT_ARGMIN(eSA,eSB, 30);
    UNIT_ARGMIN(oSA,oSB, 31);

    // cross-lane argmin over the 16 cols held by lanes sharing q (bits 0-3)
    #pragma unroll
    for (int mask = 1; mask <= 8; mask <<= 1) {
        #pragma unroll
        for (int g = 0; g < 4; ++g) {
            float od = __shfl_xor(bestd[g], mask, 64);
            int   oi = __shfl_xor(besti[g], mask, 64);
            if (od < bestd[g] ||
                (od == bestd[g] && oi < besti[g])) {
                bestd[g] = od; besti[g] = oi;
            }
        }
    }
    if (r16 == 0) {
        #pragma unroll
        for (int g = 0; g < 4; ++g)
            sidx[w*16 + q*4 + g] = besti[g];
    }
    __syncthreads();

    // fused epilogue: 4 threads/row, 16 elems each (x from global/L3, code L2)
    const int row = t >> 2, part = t & 3;
    const int grow = blockIdx.x * RPB + row;
    const int bi = sidx[row];
    float dsum = 0.f;
    {
        const float4* eq = reinterpret_cast<const float4*>(emb + (size_t)bi * D) + part*4;
        const float4* xg = x4 + (size_t)grow*16 + part*4;
        float4* o = reinterpret_cast<float4*>(out + (size_t)grow * D) + part*4;
        #pragma unroll
        for (int i = 0; i < 4; ++i) {
            float4 xv = xg[i];
            float4 qv = eq[i];
            float4 v;
            float d0,d1,d2,d3;
            d0 = qv.x - xv.x; v.x = xv.x + d0; dsum = fmaf(d0,d0,dsum);
            d1 = qv.y - xv.y; v.y = xv.y + d1; dsum = fmaf(d1,d1,dsum);
            d2 = qv.z - xv.z; v.z = xv.z + d2; dsum = fmaf(d2,d2,dsum);
            d3 = qv.w - xv.w; v.w = xv.w + d3; dsum = fmaf(d3,d3,dsum);
            o[i] = v;
        }
    }
    if (part == 0) {
        out[IDX_OFF + grow] = (float)bi;
        atomicAdd(&shist[bi], 1);
    }

    // wave reduce dsum, then block reduce via LDS -> 1 global atomic per block
    #pragma unroll
    for (int off = 32; off > 0; off >>= 1)
        dsum += __shfl_xor(dsum, off, 64);
    if (l == 0) sred[w] = dsum;
    __syncthreads();
    if (t == 0)
        atomicAdd(wsum, (sred[0] + sred[1]) + (sred[2] + sred[3]));

    for (int i = t; i < K; i += TPB)
        if (shist[i]) atomicAdd(&whist[i], shist[i]);
}

__global__ __launch_bounds__(K) void vq_finalize(
    const float* __restrict__ wsum, const int* __restrict__ whist,
    float* __restrict__ out)
{
    __shared__ float red[K];
    int t = threadIdx.x;
    float c = (float)whist[t];
    float p = c / (float)NROWS;
    red[t] = p * logf(p + 1e-10f);
    __syncthreads();
    for (int s = K/2; s > 0; s >>= 1) {
        if (t < s) red[t] += red[t+s];
        __syncthreads();
    }
    if (t == 0) {
        out[PERP_OFF] = expf(-red[0]);
        out[LOSS_OFF] = 0.25f * (wsum[0] / (float)(NROWS*D));
    }
}

extern "C" void kernel_launch(void* const* d_in, const int* in_sizes, int n_in,
                              void* d_out, int out_size, void* d_ws, size_t ws_size,
                              hipStream_t stream)
{
    const float* x   = (const float*)d_in[0];
    const float* emb = (const float*)d_in[1];
    float* out   = (float*)d_out;
    float* wsum  = (float*)d_ws;                           // @0
    int*   whist = (int*)((char*)d_ws + 256);              // @256B
    float* e2    = (float*)((char*)d_ws + 4096);           // @4096B
    h16x8* bfrag = (h16x8*)((char*)d_ws + 8192);           // @8192B, 131072B

    vq_prep<<<32, 64, 0, stream>>>(emb, e2, bfrag, wsum, whist);  // also zeroes ws
    vq_main<<<NBLK, TPB, 0, stream>>>(x, emb, e2, bfrag, out, wsum, whist);
    vq_finalize<<<1, K, 0, stream>>>(wsum, whist, out);
}